// Round 1
// baseline (77.805 us; speedup 1.0000x reference)
//
#include <hip/hip_runtime.h>
#include <cmath>

// PCEN: out = (x / (FLOOR + ema(x,w))^a + d)^(1/r) - d^(1/r), plus x_length passthrough.
// One 256-thread block per (b,c) row of T=8000. Row staged in LDS; EMA recurrence
// solved with a segmented (A,B) affine scan; pointwise math fused in pass 2.

constexpr int T_LEN = 8000;
constexpr int T4    = T_LEN / 4;   // 2000 float4 slots per row
constexpr int BLK   = 256;
constexpr int SEG   = 32;          // elements per thread segment
constexpr int NSEG  = T_LEN / SEG; // 250 active scan threads

// Rotate float4 slots within each 8-slot (128B) window by the window index.
// Keeps staging contiguous & 16B-aligned; makes per-thread segment reads
// (window == tid) hit all 8 LDS bank groups instead of one (kills the
// 64-way conflict of the naive [seg][32] layout).
__device__ __forceinline__ int swz4(int j) {
    return (j & ~7) | ((j + (j >> 3)) & 7);
}

__device__ __forceinline__ float pcen_point(float xi, float m, float a,
                                            float inv_r, float d, float droot) {
    // (x * (FLOOR+m)^-a + d)^(1/r) - d^(1/r); all log args > 0 for this problem.
    float mden = exp2f(-a * log2f(1e-12f + m));
    float base = fmaf(xi, mden, d);
    return exp2f(inv_r * log2f(base)) - droot;
}

__global__ __launch_bounds__(BLK) void pcen_kernel(
    const float* __restrict__ x, const float* __restrict__ alpha,
    const float* __restrict__ delta, const float* __restrict__ root,
    const float* __restrict__ ema_w, const int* __restrict__ xlen,
    float* __restrict__ out, int C, int rows, int nlen)
{
    __shared__ float4 lds4[T4];
    __shared__ float sA[BLK];
    __shared__ float sB[BLK];

    const int tid = threadIdx.x;
    const int row = blockIdx.x;
    const int c   = row % C;

    const float w     = fminf(fmaxf(ema_w[c], 0.0f), 1.0f);
    const float a     = fminf(alpha[c], 1.0f);
    const float r     = fmaxf(root[c], 1.0f);
    const float inv_r = 1.0f / r;
    const float d     = delta[c];
    const float droot = powf(d, inv_r);
    const float omw   = 1.0f - w;

    const float4* x4 = reinterpret_cast<const float4*>(x + (size_t)row * T_LEN);
    float4*       o4 = reinterpret_cast<float4*>(out + (size_t)row * T_LEN);

    // stage row into LDS (coalesced float4, swizzled placement)
    for (int j = tid; j < T4; j += BLK) lds4[swz4(j)] = x4[j];
    __syncthreads();

    const float x0 = lds4[0].x;  // swz4(0) == 0; broadcast read

    // ---- pass 1: per-segment affine transform acc_out = A*acc_in + B ----
    float A = 1.0f, Bv = 0.0f;
    if (tid < NSEG) {
        const int base = tid * 8;
        #pragma unroll
        for (int k = 0; k < 8; ++k) {
            float4 v = lds4[base + ((k + tid) & 7)];
            Bv = fmaf(w, v.x, omw * Bv);
            Bv = fmaf(w, v.y, omw * Bv);
            Bv = fmaf(w, v.z, omw * Bv);
            Bv = fmaf(w, v.w, omw * Bv);
        }
        float t2 = omw * omw, t4 = t2 * t2, t8 = t4 * t4, t16 = t8 * t8;
        A = t16 * t16;  // (1-w)^32
    }

    // ---- block-wide Hillis-Steele inclusive scan of (A,B) composition ----
    sA[tid] = A; sB[tid] = Bv;
    __syncthreads();
    float aa = A, bb = Bv;
    for (int off = 1; off < BLK; off <<= 1) {
        float pa = 1.0f, pb = 0.0f;
        if (tid >= off) { pa = sA[tid - off]; pb = sB[tid - off]; }
        __syncthreads();
        bb = fmaf(aa, pb, bb);  // prev-then-cur: B = b + a*pb (old a!)
        aa = aa * pa;           //               A = a * pa
        sA[tid] = aa; sB[tid] = bb;
        __syncthreads();
    }
    float ea = 1.0f, eb = 0.0f;
    if (tid > 0) { ea = sA[tid - 1]; eb = sB[tid - 1]; }
    float acc = fmaf(ea, x0, eb);  // incoming accumulator; thread 0 gets x0

    // ---- pass 2: exact EMA replay + pointwise PCEN, overwrite LDS ----
    if (tid < NSEG) {
        const int base = tid * 8;
        #pragma unroll
        for (int k = 0; k < 8; ++k) {
            const int p = base + ((k + tid) & 7);
            float4 v = lds4[p];
            float4 o;
            acc = fmaf(w, v.x, omw * acc); o.x = pcen_point(v.x, acc, a, inv_r, d, droot);
            acc = fmaf(w, v.y, omw * acc); o.y = pcen_point(v.y, acc, a, inv_r, d, droot);
            acc = fmaf(w, v.z, omw * acc); o.z = pcen_point(v.z, acc, a, inv_r, d, droot);
            acc = fmaf(w, v.w, omw * acc); o.w = pcen_point(v.w, acc, a, inv_r, d, droot);
            lds4[p] = o;
        }
    }
    __syncthreads();

    // coalesced store
    for (int j = tid; j < T4; j += BLK) o4[j] = lds4[swz4(j)];

    // output 1: x_length as float (harness reads whole d_out as f32)
    if (row == 0) {
        for (int i = tid; i < nlen; i += BLK)
            out[(size_t)rows * T_LEN + i] = (float)xlen[i];
    }
}

extern "C" void kernel_launch(void* const* d_in, const int* in_sizes, int n_in,
                              void* d_out, int out_size, void* d_ws, size_t ws_size,
                              hipStream_t stream) {
    const float* x     = (const float*)d_in[0];
    const float* alpha = (const float*)d_in[1];
    const float* delta = (const float*)d_in[2];
    const float* root  = (const float*)d_in[3];
    const float* emaw  = (const float*)d_in[4];
    const int*   xlen  = (const int*)d_in[5];
    float*       out   = (float*)d_out;

    const int C    = in_sizes[1];
    const int rows = in_sizes[0] / T_LEN;  // B*C
    const int nlen = in_sizes[5];

    hipLaunchKernelGGL(pcen_kernel, dim3(rows), dim3(BLK), 0, stream,
                       x, alpha, delta, root, emaw, xlen, out, C, rows, nlen);
}